// Round 8
// baseline (233.079 us; speedup 1.0000x reference)
//
#include <hip/hip_runtime.h>
#include <stdint.h>

typedef float f32x4 __attribute__((ext_vector_type(4)));
typedef short s16x8 __attribute__((ext_vector_type(8)));
typedef short s16x4 __attribute__((ext_vector_type(4)));

__device__ __forceinline__ short f2bf(float f){
  union { float f; unsigned u; } v; v.f = f;
  unsigned r = v.u + 0x7FFFu + ((v.u >> 16) & 1u);
  return (short)(r >> 16);
}
__device__ __forceinline__ float bf2f(short h){
  union { unsigned u; float f; } v; v.u = ((unsigned)(unsigned short)h) << 16;
  return v.f;
}

// ---------- elementwise: o = bf16(a+b), 8 elems/thread ----------
__global__ void k_addcvt(const float* __restrict__ a, const float* __restrict__ b,
                         short* __restrict__ o){
  long i = (long)blockIdx.x * blockDim.x + threadIdx.x;
  const f32x4* a4 = (const f32x4*)a;
  const f32x4* b4 = (const f32x4*)b;
  f32x4 x0 = a4[2*i], x1 = a4[2*i+1];
  f32x4 y0 = b4[2*i], y1 = b4[2*i+1];
  s16x8 r;
  #pragma unroll
  for (int j=0;j<4;j++){ r[j] = f2bf(x0[j]+y0[j]); r[j+4] = f2bf(x1[j]+y1[j]); }
  *(s16x8*)(o + i*8) = r;
}

// ---------- fused prep: cvt x3 (blocks 0..3071), transcvt x3 (3072..6143),
// bias1 (6144..6655) ----------
__global__ void k_prep(const float* __restrict__ c0s, short* __restrict__ c0d,
                       const float* __restrict__ c1s, short* __restrict__ c1d,
                       const float* __restrict__ c2s, short* __restrict__ c2d,
                       const float* __restrict__ t0s, short* __restrict__ t0d,
                       const float* __restrict__ t1s, short* __restrict__ t1d,
                       const float* __restrict__ t2s, short* __restrict__ t2d,
                       const float* __restrict__ wt, const float* __restrict__ bvt, const float* __restrict__ obt,
                       const float* __restrict__ wi, const float* __restrict__ bvi, const float* __restrict__ obi,
                       float* __restrict__ bc){
  int bid = blockIdx.x;
  int tid = threadIdx.x;
  if (bid < 3072) {
    int z = bid >> 10, b = bid & 1023;
    const float* in = (z==0) ? c0s : ((z==1) ? c1s : c2s);
    short* out      = (z==0) ? c0d : ((z==1) ? c1d : c2d);
    long i = (long)b*256 + tid;
    f32x4 v = ((const f32x4*)in)[i];
    s16x4 r;
    #pragma unroll
    for (int j=0;j<4;j++) r[j] = f2bf(v[j]);
    *(s16x4*)(out + i*4) = r;
  } else if (bid < 6144) {
    int q = bid - 3072;
    int z = q >> 10, b = q & 1023;
    const float* in = (z==0) ? t0s : ((z==1) ? t1s : t2s);
    short* out      = (z==0) ? t0d : ((z==1) ? t1d : t2d);
    __shared__ float tile[32][33];
    int tx = tid & 31, ty = tid >> 5;
    int c0 = (b & 31)*32, r0 = (b >> 5)*32;
    #pragma unroll
    for (int i=ty; i<32; i+=8)
      tile[i][tx] = in[(long)(r0+i)*1024 + c0 + tx];
    __syncthreads();
    #pragma unroll
    for (int i=ty; i<32; i+=8)
      out[(long)(c0+i)*1024 + r0 + tx] = f2bf(tile[tx][i]);
  } else {
    int q = bid - 6144;
    int z = q >> 8, b = q & 255;
    const float* w  = z ? wi  : wt;
    const float* bv = z ? bvi : bvt;
    const float* ob = z ? obi : obt;
    int n = b*4 + (tid>>6);
    int lane = tid & 63;
    const float* row = w + (long)n*1024;
    float acc = 0.f;
    for (int j=lane; j<1024; j+=64) acc += row[j]*bv[j];
    #pragma unroll
    for (int m=32;m;m>>=1) acc += __shfl_xor(acc, m, 64);
    if (lane==0) bc[z*1024+n] = acc + ob[n];
  }
}

// ---------- bias2 + fuse_b copy folded in ----------
__global__ void k_bias2c(const short* __restrict__ Wc, const float* __restrict__ fuse_b,
                         const float* __restrict__ bc, float* __restrict__ b_all){
  if (blockIdx.x >= 512) {
    int i = (blockIdx.x - 512)*256 + threadIdx.x;
    b_all[i] = fuse_b[i];
    return;
  }
  int n = blockIdx.x*4 + (threadIdx.x>>6);
  int lane = threadIdx.x & 63;
  const short* row = Wc + (long)n*1024;
  float acc = 0.f;
  for (int j=lane; j<1024; j+=64) acc += bf2f(row[j])*fuse_b[j];
  #pragma unroll
  for (int m=32;m;m>>=1) acc += __shfl_xor(acc, m, 64);
  if (lane==0) b_all[1024+n] = acc + bc[n];
}

#define GLDS(src, dst) __builtin_amdgcn_global_load_lds( \
    (const __attribute__((address_space(1))) void*)(src), \
    (__attribute__((address_space(3))) void*)(dst), 16, 0, 0)

// ---------- small NT GEMM (128x128 tile, m97 structure): C bf16 = A@B^T ----------
__global__ __launch_bounds__(256, 2)
void gemm_nt_small(const short* __restrict__ Abase, const short* __restrict__ Bbase,
                   short* __restrict__ Cbase,
                   int M, int N, int K, long zA, long zB, long zC)
{
  __shared__ __align__(16) short ldsA[128*32];
  __shared__ __align__(16) short ldsB[128*32];
  const short* A = Abase + (long)blockIdx.z * zA;
  const short* B = Bbase + (long)blockIdx.z * zB;
  const int m0 = blockIdx.x * 128;
  const int n0 = blockIdx.y * 128;
  const int tid = threadIdx.x;
  const int lane = tid & 63;
  const int wv = tid >> 6;
  const int wm = wv >> 1, wn = wv & 1;

  f32x4 acc[4][4];
  #pragma unroll
  for (int i=0;i<4;i++)
    #pragma unroll
    for (int j=0;j<4;j++) acc[i][j] = (f32x4){0.f,0.f,0.f,0.f};

  const int bo0 = wv*1024 + lane*16;
  const int bo1 = bo0 + 4096;
  const int r0 = bo0 >> 6, c0 = bo0 & 63;
  const int r1 = bo1 >> 6, c1 = bo1 & 63;
  const long rsb = (long)K * 2;

  const char* Ab = (const char*)A;
  const char* Bb = (const char*)B;
  char* lA = (char*)&ldsA[0];
  char* lB = (char*)&ldsB[0];

  const int nkt = K >> 5;
  for (int kt = 0; kt < nkt; ++kt) {
    const long kb = (long)kt * 64;
    GLDS(Ab + (long)(m0 + r0)*rsb + kb + c0, lA + wv*1024);
    GLDS(Ab + (long)(m0 + r1)*rsb + kb + c1, lA + 4096 + wv*1024);
    GLDS(Bb + (long)(n0 + r0)*rsb + kb + c0, lB + wv*1024);
    GLDS(Bb + (long)(n0 + r1)*rsb + kb + c1, lB + 4096 + wv*1024);
    __syncthreads();

    s16x8 af[4], bfv[4];
    #pragma unroll
    for (int i=0;i<4;i++)
      af[i] = *(const s16x8*)(lA + (wm*64 + i*16 + (lane&15))*64 + (lane>>4)*16);
    #pragma unroll
    for (int j=0;j<4;j++)
      bfv[j] = *(const s16x8*)(lB + (wn*64 + j*16 + (lane&15))*64 + (lane>>4)*16);

    #pragma unroll
    for (int i=0;i<4;i++)
      #pragma unroll
      for (int j=0;j<4;j++)
        acc[i][j] = __builtin_amdgcn_mfma_f32_16x16x32_bf16(af[i], bfv[j], acc[i][j], 0, 0, 0);
    __syncthreads();
  }

  short* C = Cbase + (long)blockIdx.z * zC;
  #pragma unroll
  for (int j=0;j<4;j++){
    int gn = n0 + wn*64 + j*16 + (lane&15);
    #pragma unroll
    for (int i=0;i<4;i++){
      int gmb = m0 + wm*64 + i*16 + ((lane>>4)*4);
      #pragma unroll
      for (int r=0;r<4;r++)
        C[(long)(gmb+r)*N + gn] = f2bf(acc[i][j][r]);
    }
  }
}

// ---------- main NT GEMM: 128x128 tile, BK=64, 2 phases/K-tile, 64KB LDS ----------
// -> 2 blocks/CU co-resident (the R8 lever): one block's MFMA phases overlap the
// other's LDS/drain/epilogue. Schedule = R7's proven trace, halved:
// LDS: Abuf0 @0, Abuf1 @16K, Bbuf0 @32K, Bbuf1 @48K (16 KB each).
// Per-thread loads per stage-call pair: A = 4 GLDS, B = 4 GLDS (2 H-halves x 2).
// Prologue: A(0),B(0),B(1) issued; VMW4 leaves B(1) in flight.
// ph(t,ks0): read B(t) x8 + A(t,ks0) x4; barrier; stage A(t+1)->Abuf[(t+1)&1];
//            lgkm0; 16 MFMA.   (entry in-flight = B(t+1) only; nothing to drain)
// ph(t,ks1): read A(t,ks1) x4; VMW0 (drains B(t+1)+A(t+1)); barrier;
//            stage B(t+2)->Bbuf[t&1]; lgkm0; 16 MFMA.
// Write-safety: every stage issues after a barrier that postdates the last reads
// of its target buffer (reads complete at each wave's pre-MFMA lgkm0 a phase
// earlier). Read-safety: A(t+1)/B(t+1) drained at ph(t,ks1) VMW0, fenced by its
// barrier, read earliest at ph(t+1,ks0). Identical invariants to R7 (verified).
#define MFMA16 __builtin_amdgcn_mfma_f32_16x16x32_bf16
#define VMW4 asm volatile("s_waitcnt vmcnt(4)" ::: "memory")
#define VMW0 asm volatile("s_waitcnt vmcnt(0)" ::: "memory")
#define LGKM0 asm volatile("s_waitcnt lgkmcnt(0)" ::: "memory")
#define MEMF asm volatile("" ::: "memory")

__global__ __launch_bounds__(256, 2)
void gemm_main(const short* __restrict__ A, const short* __restrict__ B,
               float* __restrict__ O, const float* __restrict__ bias,
               int M, int N, int K)
{
  __shared__ __align__(16) char lds[65536];

  const int nbn = N >> 7;                 // 24
  const int nwg = (M >> 7) * nbn;         // 3072 (nwg % 8 == 0)
  const int cpx = nwg >> 3;
  int bid = blockIdx.x;
  int swz = (bid & 7) * cpx + (bid >> 3);
  const int m0 = (swz / nbn) << 7;
  const int n0 = (swz % nbn) << 7;

  const int tid  = threadIdx.x;
  const int lane = tid & 63;
  const int wid  = tid >> 6;              // 0..3
  const int wm   = wid >> 1;              // 0..1
  const int wn   = wid & 1;               // 0..1
  const long rsb = (long)K * 2;
  const char* Ab = (const char*)A;
  const char* Bb = (const char*)B;

  f32x4 acc[4][4];
  #pragma unroll
  for (int i=0;i<4;i++)
    #pragma unroll
    for (int j=0;j<4;j++) acc[i][j] = (f32x4){0.f,0.f,0.f,0.f};

  // Stage source precompute: linear LDS dest chunk c (16 KB buffer = 1024
  // chunks) receives logical chunk q = c ^ ((c>>3)&7) (row = c>>3 preserved;
  // inverse of the read swizzle). c = H*512 + sb*256 + tid.
  long srow[2][2]; int scol[2][2]; int sdst[2][2];
  #pragma unroll
  for (int H=0;H<2;H++)
    #pragma unroll
    for (int sb=0;sb<2;sb++){
      int c = H*512 + sb*256 + tid;
      int q = c ^ ((c>>3)&7);
      srow[H][sb] = (long)(q >> 3);
      scol[H][sb] = (q & 7) << 4;
      sdst[H][sb] = (H*512 + sb*256 + wid*64) << 4;   // wave-uniform LDS base
    }

  auto stage = [&](const char* P, int tr0, int s /*K-tile*/, int RB, int H){
    const long ktb = (long)s << 7;        // s * 64 elems * 2B
    GLDS(P + ((long)tr0 + srow[H][0])*rsb + ktb + scol[H][0], lds + RB + sdst[H][0]);
    GLDS(P + ((long)tr0 + srow[H][1])*rsb + ktb + scol[H][1], lds + RB + sdst[H][1]);
  };

  const int swx = (lane & 7) << 4;        // read swizzle (row&7 == lane&7)
  auto ldA = [&](int RB, int i, int ks) -> s16x8 {
    int off = (wm*64 + i*16 + (lane&15))*128 + ks*64 + ((lane>>4)<<4);
    off ^= swx;
    return *(const s16x8*)(lds + RB + off);
  };
  auto ldB = [&](int RB, int j, int ks) -> s16x8 {
    int off = (wn*64 + j*16 + (lane&15))*128 + ks*64 + ((lane>>4)<<4);
    off ^= swx;
    return *(const s16x8*)(lds + 32768 + RB + off);
  };

  s16x8 bfr[4][2];
  s16x8 af[4];
  const int nkt = K >> 6;                 // 16

  // Prologue: A(0)->Abuf0, B(0)->Bbuf0, B(1)->Bbuf1 (12 loads); VMW4 drains
  // A(0)+B(0), leaves B(1)x4 in flight (drained at ph(0,ks1) VMW0).
  stage(Ab, m0, 0, 0,     0); stage(Ab, m0, 0, 0,     1);
  stage(Bb, n0, 0, 32768, 0); stage(Bb, n0, 0, 32768, 1);
  stage(Bb, n0, 1, 49152, 0); stage(Bb, n0, 1, 49152, 1);
  VMW4; MEMF;
  __builtin_amdgcn_s_barrier();

  for (int t = 0; t < nkt; ++t) {
    const int RB = (t & 1) << 14;         // 0 / 16384
    // -------- ks0 phase --------
    #pragma unroll
    for (int j=0;j<4;j++){ bfr[j][0] = ldB(RB, j, 0); bfr[j][1] = ldB(RB, j, 1); }
    #pragma unroll
    for (int i=0;i<4;i++) af[i] = ldA(RB, i, 0);
    MEMF;
    __builtin_amdgcn_s_barrier();
    if (t+1 < nkt) {
      const int AB2 = ((t+1)&1) << 14;
      stage(Ab, m0, t+1, AB2, 0); stage(Ab, m0, t+1, AB2, 1);
    }
    LGKM0;
    __builtin_amdgcn_s_setprio(1);
    #pragma unroll
    for (int i=0;i<4;i++)
      #pragma unroll
      for (int j=0;j<4;j++)
        acc[i][j] = MFMA16(af[i], bfr[j][0], acc[i][j], 0, 0, 0);
    __builtin_amdgcn_s_setprio(0);
    // -------- ks1 phase --------
    #pragma unroll
    for (int i=0;i<4;i++) af[i] = ldA(RB, i, 1);
    VMW0; MEMF;                           // drains B(t+1) AND A(t+1)
    __builtin_amdgcn_s_barrier();
    if (t+2 < nkt) {
      const int BB2 = 32768 + RB;         // Bbuf[t&1]: all reads done at ks0
      stage(Bb, n0, t+2, BB2, 0); stage(Bb, n0, t+2, BB2, 1);
    }
    LGKM0;
    __builtin_amdgcn_s_setprio(1);
    #pragma unroll
    for (int i=0;i<4;i++)
      #pragma unroll
      for (int j=0;j<4;j++)
        acc[i][j] = MFMA16(af[i], bfr[j][1], acc[i][j], 0, 0, 0);
    __builtin_amdgcn_s_setprio(0);
  }

  // Epilogue: fp32 + bias, scatter by output region (text | image | fused).
  const long BD = (long)M * 1024L;
  #pragma unroll
  for (int j=0;j<4;j++){
    int gn = n0 + wn*64 + j*16 + (lane&15);
    float bb = bias[gn];
    int region = gn >> 10;
    long rbase = (region==0) ? 2*BD : ((region==1) ? 0L : BD);
    int col = gn & 1023;
    #pragma unroll
    for (int i=0;i<4;i++){
      int gr = m0 + wm*64 + i*16 + ((lane>>4)<<2);
      #pragma unroll
      for (int r=0;r<4;r++)
        O[rbase + (long)(gr+r)*1024 + col] = acc[i][j][r] + bb;
    }
  }
}

extern "C" void kernel_launch(void* const* d_in, const int* in_sizes, int n_in,
                              void* d_out, int out_size, void* d_ws, size_t ws_size,
                              hipStream_t stream) {
  const float* text    = (const float*)d_in[0];
  const float* image   = (const float*)d_in[1];
  const float* fuse_w  = (const float*)d_in[2];
  const float* fuse_b  = (const float*)d_in[3];
  const float* t_in_w  = (const float*)d_in[4];
  const float* t_in_b  = (const float*)d_in[5];
  const float* t_out_w = (const float*)d_in[6];
  const float* t_out_b = (const float*)d_in[7];
  const float* i_in_w  = (const float*)d_in[8];
  const float* i_in_b  = (const float*)d_in[9];
  const float* i_out_w = (const float*)d_in[10];
  const float* i_out_b = (const float*)d_in[11];
  float* out = (float*)d_out;

  const long DD = 1024L*1024L;
  char* ws = (char*)d_ws;
  short* s_bf    = (short*)ws; ws += 16384L*1024*2;
  short* W_all   = (short*)ws; ws += 3*DD*2;      // rows: [fuse_w; Wt2; Wi2]
  short* wvT     = (short*)ws; ws += 2*DD*2;      // [wvT_t; wvT_i]
  short* fuse_wT = (short*)ws; ws += DD*2;
  short* outw_st = (short*)ws; ws += 2*DD*2;      // [t_out_w; i_out_w] bf16
  short* Wc_st   = (short*)ws; ws += 2*DD*2;      // [Wc_t; Wc_i]
  float* bc      = (float*)ws; ws += 2048*4;
  float* b_all   = (float*)ws; ws += 3072*4;

  // prep
  k_addcvt<<<8192, 256, 0, stream>>>(text, image, s_bf);
  k_prep<<<6656, 256, 0, stream>>>(fuse_w, W_all,
                                   t_out_w, outw_st,
                                   i_out_w, outw_st + DD,
                                   t_in_w + 2*DD, wvT,
                                   i_in_w + 2*DD, wvT + DD,
                                   fuse_w, fuse_wT,
                                   t_out_w, t_in_b + 2048, t_out_b,
                                   i_out_w, i_in_b + 2048, i_out_b, bc);

  // Wc_z = out_w_z @ wv_z
  gemm_nt_small<<<dim3(8,8,2), 256, 0, stream>>>(outw_st, wvT, Wc_st,
                                                 1024, 1024, 1024, DD, DD, DD);
  // b_all[1024..3072) = Wc @ fuse_b + bc ; b_all[0..1024) = fuse_b
  k_bias2c<<<516, 256, 0, stream>>>(Wc_st, fuse_b, bc, b_all);
  // [Wt2; Wi2] = Wc @ fuse_w
  gemm_nt_small<<<dim3(16,8,1), 256, 0, stream>>>(Wc_st, fuse_wT, W_all + DD,
                                                  2048, 1024, 1024, 0, 0, 0);
  // main: C = s @ W_all.T + b_all, scatter into d_out
  gemm_main<<<dim3(3072), 256, 0, stream>>>(s_bf, W_all, out, b_all, 16384, 3072, 1024);
}

// Round 9
// 227.678 us; speedup vs baseline: 1.0237x; 1.0237x over previous
//
#include <hip/hip_runtime.h>
#include <stdint.h>

typedef float f32x4 __attribute__((ext_vector_type(4)));
typedef short s16x8 __attribute__((ext_vector_type(8)));
typedef short s16x4 __attribute__((ext_vector_type(4)));

__device__ __forceinline__ short f2bf(float f){
  union { float f; unsigned u; } v; v.f = f;
  unsigned r = v.u + 0x7FFFu + ((v.u >> 16) & 1u);
  return (short)(r >> 16);
}
__device__ __forceinline__ float bf2f(short h){
  union { unsigned u; float f; } v; v.u = ((unsigned)(unsigned short)h) << 16;
  return v.f;
}

// ---------- elementwise: o = bf16(a+b), 8 elems/thread ----------
__global__ void k_addcvt(const float* __restrict__ a, const float* __restrict__ b,
                         short* __restrict__ o){
  long i = (long)blockIdx.x * blockDim.x + threadIdx.x;
  const f32x4* a4 = (const f32x4*)a;
  const f32x4* b4 = (const f32x4*)b;
  f32x4 x0 = a4[2*i], x1 = a4[2*i+1];
  f32x4 y0 = b4[2*i], y1 = b4[2*i+1];
  s16x8 r;
  #pragma unroll
  for (int j=0;j<4;j++){ r[j] = f2bf(x0[j]+y0[j]); r[j+4] = f2bf(x1[j]+y1[j]); }
  *(s16x8*)(o + i*8) = r;
}

// ---------- fused prep: cvt x3 (blocks 0..3071), transcvt x3 (3072..6143),
// bias1 (6144..6655) ----------
__global__ void k_prep(const float* __restrict__ c0s, short* __restrict__ c0d,
                       const float* __restrict__ c1s, short* __restrict__ c1d,
                       const float* __restrict__ c2s, short* __restrict__ c2d,
                       const float* __restrict__ t0s, short* __restrict__ t0d,
                       const float* __restrict__ t1s, short* __restrict__ t1d,
                       const float* __restrict__ t2s, short* __restrict__ t2d,
                       const float* __restrict__ wt, const float* __restrict__ bvt, const float* __restrict__ obt,
                       const float* __restrict__ wi, const float* __restrict__ bvi, const float* __restrict__ obi,
                       float* __restrict__ bc){
  int bid = blockIdx.x;
  int tid = threadIdx.x;
  if (bid < 3072) {
    int z = bid >> 10, b = bid & 1023;
    const float* in = (z==0) ? c0s : ((z==1) ? c1s : c2s);
    short* out      = (z==0) ? c0d : ((z==1) ? c1d : c2d);
    long i = (long)b*256 + tid;
    f32x4 v = ((const f32x4*)in)[i];
    s16x4 r;
    #pragma unroll
    for (int j=0;j<4;j++) r[j] = f2bf(v[j]);
    *(s16x4*)(out + i*4) = r;
  } else if (bid < 6144) {
    int q = bid - 3072;
    int z = q >> 10, b = q & 1023;
    const float* in = (z==0) ? t0s : ((z==1) ? t1s : t2s);
    short* out      = (z==0) ? t0d : ((z==1) ? t1d : t2d);
    __shared__ float tile[32][33];
    int tx = tid & 31, ty = tid >> 5;
    int c0 = (b & 31)*32, r0 = (b >> 5)*32;
    #pragma unroll
    for (int i=ty; i<32; i+=8)
      tile[i][tx] = in[(long)(r0+i)*1024 + c0 + tx];
    __syncthreads();
    #pragma unroll
    for (int i=ty; i<32; i+=8)
      out[(long)(c0+i)*1024 + r0 + tx] = f2bf(tile[tx][i]);
  } else {
    int q = bid - 6144;
    int z = q >> 8, b = q & 255;
    const float* w  = z ? wi  : wt;
    const float* bv = z ? bvi : bvt;
    const float* ob = z ? obi : obt;
    int n = b*4 + (tid>>6);
    int lane = tid & 63;
    const float* row = w + (long)n*1024;
    float acc = 0.f;
    for (int j=lane; j<1024; j+=64) acc += row[j]*bv[j];
    #pragma unroll
    for (int m=32;m;m>>=1) acc += __shfl_xor(acc, m, 64);
    if (lane==0) bc[z*1024+n] = acc + ob[n];
  }
}

// ---------- bias2 + fuse_b copy folded in ----------
__global__ void k_bias2c(const short* __restrict__ Wc, const float* __restrict__ fuse_b,
                         const float* __restrict__ bc, float* __restrict__ b_all){
  if (blockIdx.x >= 512) {
    int i = (blockIdx.x - 512)*256 + threadIdx.x;
    b_all[i] = fuse_b[i];
    return;
  }
  int n = blockIdx.x*4 + (threadIdx.x>>6);
  int lane = threadIdx.x & 63;
  const short* row = Wc + (long)n*1024;
  float acc = 0.f;
  for (int j=lane; j<1024; j+=64) acc += bf2f(row[j])*fuse_b[j];
  #pragma unroll
  for (int m=32;m;m>>=1) acc += __shfl_xor(acc, m, 64);
  if (lane==0) b_all[1024+n] = acc + bc[n];
}

#define GLDS(src, dst) __builtin_amdgcn_global_load_lds( \
    (const __attribute__((address_space(1))) void*)(src), \
    (__attribute__((address_space(3))) void*)(dst), 16, 0, 0)

// ---------- small NT GEMM (128x128 tile, m97 structure): C bf16 = A@B^T ----------
__global__ __launch_bounds__(256, 2)
void gemm_nt_small(const short* __restrict__ Abase, const short* __restrict__ Bbase,
                   short* __restrict__ Cbase,
                   int M, int N, int K, long zA, long zB, long zC)
{
  __shared__ __align__(16) short ldsA[128*32];
  __shared__ __align__(16) short ldsB[128*32];
  const short* A = Abase + (long)blockIdx.z * zA;
  const short* B = Bbase + (long)blockIdx.z * zB;
  const int m0 = blockIdx.x * 128;
  const int n0 = blockIdx.y * 128;
  const int tid = threadIdx.x;
  const int lane = tid & 63;
  const int wv = tid >> 6;
  const int wm = wv >> 1, wn = wv & 1;

  f32x4 acc[4][4];
  #pragma unroll
  for (int i=0;i<4;i++)
    #pragma unroll
    for (int j=0;j<4;j++) acc[i][j] = (f32x4){0.f,0.f,0.f,0.f};

  const int bo0 = wv*1024 + lane*16;
  const int bo1 = bo0 + 4096;
  const int r0 = bo0 >> 6, c0 = bo0 & 63;
  const int r1 = bo1 >> 6, c1 = bo1 & 63;
  const long rsb = (long)K * 2;

  const char* Ab = (const char*)A;
  const char* Bb = (const char*)B;
  char* lA = (char*)&ldsA[0];
  char* lB = (char*)&ldsB[0];

  const int nkt = K >> 5;
  for (int kt = 0; kt < nkt; ++kt) {
    const long kb = (long)kt * 64;
    GLDS(Ab + (long)(m0 + r0)*rsb + kb + c0, lA + wv*1024);
    GLDS(Ab + (long)(m0 + r1)*rsb + kb + c1, lA + 4096 + wv*1024);
    GLDS(Bb + (long)(n0 + r0)*rsb + kb + c0, lB + wv*1024);
    GLDS(Bb + (long)(n0 + r1)*rsb + kb + c1, lB + 4096 + wv*1024);
    __syncthreads();

    s16x8 af[4], bfv[4];
    #pragma unroll
    for (int i=0;i<4;i++)
      af[i] = *(const s16x8*)(lA + (wm*64 + i*16 + (lane&15))*64 + (lane>>4)*16);
    #pragma unroll
    for (int j=0;j<4;j++)
      bfv[j] = *(const s16x8*)(lB + (wn*64 + j*16 + (lane&15))*64 + (lane>>4)*16);

    #pragma unroll
    for (int i=0;i<4;i++)
      #pragma unroll
      for (int j=0;j<4;j++)
        acc[i][j] = __builtin_amdgcn_mfma_f32_16x16x32_bf16(af[i], bfv[j], acc[i][j], 0, 0, 0);
    __syncthreads();
  }

  short* C = Cbase + (long)blockIdx.z * zC;
  #pragma unroll
  for (int j=0;j<4;j++){
    int gn = n0 + wn*64 + j*16 + (lane&15);
    #pragma unroll
    for (int i=0;i<4;i++){
      int gmb = m0 + wm*64 + i*16 + ((lane>>4)*4);
      #pragma unroll
      for (int r=0;r<4;r++)
        C[(long)(gmb+r)*N + gn] = f2bf(acc[i][j][r]);
    }
  }
}

// ---------- main NT GEMM: 256x256, BK=64, 2 phases/K-tile, OVERLAPPED reads ----------
// LDS: Abuf0 @0, Abuf1 @32768, Bbuf0 @65536, Bbuf1 @98304 (32 KB each).
// Swizzle: 16B-chunk s of row r stored at s^(r&7); conflict-free (verified R3: 0).
// R9 change vs R7: NO explicit lgkmcnt(0); i-outer MFMA loops; reads placed so
// the compiler's progressive per-register lgkm waits let ds_reads run UNDER the
// MFMA burst (breaking the read/MFMA alternation that capped MfmaUtil at 30%).
//   X0(t): barrier; stage A(t+1)->Abuf[(t+1)&1]; read bfr[ ][1]=B(t,ks1) x4 and
//          af=A(t,ks0) x8; MFMA 32 (af x bfr[ ][0]).
//   X1(t): read af=A(t,ks1) x8 (pre-barrier: fills LDS pipe during drain);
//          VMW0; barrier; stage B(t+2)->Bbuf[t&1]; refill bfr[ ][0]=B(t+1,ks0)
//          x4 (consumed next K-tile); MFMA 32 (af x bfr[ ][1]).
// Read-safety: everything read at X0(t)/X1(t) was drained by X1(t-1)'s VMW0 and
// fenced by its barrier. Write-safety: each stage targets a buffer whose last
// reads were consumed by MFMAs before the stage's preceding barrier — except
// bfr[ ][1] (read X0-start, consumed X1): its buffer is overwritten by X1's
// stage whose write data lands >= (X0 phase length ~1400cyc + 200cyc) after the
// read issues; LDS read queue drains <= ~600cyc -> structural margin ~1000cyc.
#define MFMA16 __builtin_amdgcn_mfma_f32_16x16x32_bf16
#define VMW0 asm volatile("s_waitcnt vmcnt(0)" ::: "memory")
#define MEMF asm volatile("" ::: "memory")

__global__ __launch_bounds__(512, 2)
void gemm_main(const short* __restrict__ A, const short* __restrict__ B,
               float* __restrict__ O, const float* __restrict__ bias,
               int M, int N, int K)
{
  __shared__ __align__(16) char lds[131072];

  const int nbn = N >> 8;
  const int nwg = (M >> 8) * nbn;
  const int cpx = nwg >> 3;
  int bid = blockIdx.x;
  int swz = (bid & 7) * cpx + (bid >> 3);
  const int m0 = (swz / nbn) << 8;
  const int n0 = (swz % nbn) << 8;

  const int tid  = threadIdx.x;
  const int lane = tid & 63;
  const int wid  = tid >> 6;
  const int wm   = wid >> 2;   // 0..1
  const int wn   = wid & 3;    // 0..3
  const long rsb = (long)K * 2;
  const char* Ab = (const char*)A;
  const char* Bb = (const char*)B;

  f32x4 acc[8][4];
  #pragma unroll
  for (int i=0;i<8;i++)
    #pragma unroll
    for (int j=0;j<4;j++) acc[i][j] = (f32x4){0.f,0.f,0.f,0.f};

  // Stage source precompute: linear LDS dest chunk c receives logical chunk
  // q = c ^ ((c>>3)&7)  (row preserved; inverse of the read swizzle).
  int srow[2][2]; int scol[2][2]; int sdst[2][2];
  #pragma unroll
  for (int H=0;H<2;H++)
    #pragma unroll
    for (int sb=0;sb<2;sb++){
      int c = H*1024 + sb*512 + wid*64 + lane;
      int q = c ^ ((c>>3)&7);
      srow[H][sb] = q >> 3;
      scol[H][sb] = (q & 7) << 4;
      sdst[H][sb] = (H*1024 + sb*512 + wid*64) << 4;
    }

  auto stage = [&](const char* P, int tr0, int s /*K-tile*/, int RB, int H){
    const long ktb = (long)s << 7;
    GLDS(P + ((long)(tr0 + srow[H][0]))*rsb + ktb + scol[H][0], lds + RB + sdst[H][0]);
    GLDS(P + ((long)(tr0 + srow[H][1]))*rsb + ktb + scol[H][1], lds + RB + sdst[H][1]);
  };

  const int swx = (lane & 7) << 4;   // read swizzle (row&7 == lane&7 for all frags)
  auto ldA = [&](int RB, int i, int ks) -> s16x8 {
    int off = (wm*128 + i*16 + (lane&15))*128 + ks*64 + ((lane>>4)<<4);
    off ^= swx;
    return *(const s16x8*)(lds + RB + off);
  };
  auto ldB = [&](int RB, int j, int ks) -> s16x8 {
    int off = (wn*64 + j*16 + (lane&15))*128 + ks*64 + ((lane>>4)<<4);
    off ^= swx;
    return *(const s16x8*)(lds + 65536 + RB + off);
  };

  s16x8 bfr[4][2];
  s16x8 af[8];
  const int nkt = K >> 6;  // 16 for K=1024

  // Prologue: A(0)->Abuf0, B(0)->Bbuf0, B(1)->Bbuf1; full drain; preload
  // bfr[ ][0] = B(0,ks0).
  stage(Ab, m0, 0, 0,     0); stage(Ab, m0, 0, 0,     1);
  stage(Bb, n0, 0, 65536, 0); stage(Bb, n0, 0, 65536, 1);
  stage(Bb, n0, 1, 98304, 0); stage(Bb, n0, 1, 98304, 1);
  VMW0; MEMF;
  __builtin_amdgcn_s_barrier();
  #pragma unroll
  for (int j=0;j<4;j++) bfr[j][0] = ldB(0, j, 0);

  for (int t = 0; t < nkt; ++t) {
    const int RB = (t & 1) << 15;
    // -------- X0 (ks0) --------
    MEMF;
    __builtin_amdgcn_s_barrier();   // fences X1(t-1)'s af reads before stage A(t+1)
    if (t+1 < nkt) {
      const int AB2 = ((t+1)&1) << 15;
      stage(Ab, m0, t+1, AB2, 0); stage(Ab, m0, t+1, AB2, 1);
    }
    #pragma unroll
    for (int j=0;j<4;j++) bfr[j][1] = ldB(RB, j, 1);   // B(t,ks1) for X1
    #pragma unroll
    for (int i=0;i<8;i++) af[i] = ldA(RB, i, 0);       // A(t,ks0), progressive
    __builtin_amdgcn_s_setprio(1);
    #pragma unroll
    for (int i=0;i<8;i++)
      #pragma unroll
      for (int j=0;j<4;j++)
        acc[i][j] = MFMA16(af[i], bfr[j][0], acc[i][j], 0, 0, 0);
    __builtin_amdgcn_s_setprio(0);
    // -------- X1 (ks1) --------
    #pragma unroll
    for (int i=0;i<8;i++) af[i] = ldA(RB, i, 1);       // pre-barrier: fills pipe
    VMW0; MEMF;                     // drains A(t+1) + B(t+1)
    __builtin_amdgcn_s_barrier();
    if (t+2 < nkt) {
      const int BB2 = 65536 + RB;   // Bbuf[t&1]: last reads (bfr) consumed by X0/X1 MFMAs
      stage(Bb, n0, t+2, BB2, 0); stage(Bb, n0, t+2, BB2, 1);
    }
    if (t+1 < nkt) {
      const int RB2 = ((t+1)&1) << 15;
      #pragma unroll
      for (int j=0;j<4;j++) bfr[j][0] = ldB(RB2, j, 0); // B(t+1,ks0) for next tile
    }
    __builtin_amdgcn_s_setprio(1);
    #pragma unroll
    for (int i=0;i<8;i++)
      #pragma unroll
      for (int j=0;j<4;j++)
        acc[i][j] = MFMA16(af[i], bfr[j][1], acc[i][j], 0, 0, 0);
    __builtin_amdgcn_s_setprio(0);
  }

  // Epilogue: fp32 + bias, scatter by output region (text | image | fused).
  const long BD = (long)M * 1024L;
  #pragma unroll
  for (int j=0;j<4;j++){
    int gn = n0 + wn*64 + j*16 + (lane&15);
    float bb = bias[gn];
    int region = gn >> 10;
    long rbase = (region==0) ? 2*BD : ((region==1) ? 0L : BD);
    int col = gn & 1023;
    #pragma unroll
    for (int i=0;i<8;i++){
      int gr = m0 + wm*128 + i*16 + ((lane>>4)<<2);
      #pragma unroll
      for (int r=0;r<4;r++)
        O[rbase + (long)(gr+r)*1024 + col] = acc[i][j][r] + bb;
    }
  }
}

extern "C" void kernel_launch(void* const* d_in, const int* in_sizes, int n_in,
                              void* d_out, int out_size, void* d_ws, size_t ws_size,
                              hipStream_t stream) {
  const float* text    = (const float*)d_in[0];
  const float* image   = (const float*)d_in[1];
  const float* fuse_w  = (const float*)d_in[2];
  const float* fuse_b  = (const float*)d_in[3];
  const float* t_in_w  = (const float*)d_in[4];
  const float* t_in_b  = (const float*)d_in[5];
  const float* t_out_w = (const float*)d_in[6];
  const float* t_out_b = (const float*)d_in[7];
  const float* i_in_w  = (const float*)d_in[8];
  const float* i_in_b  = (const float*)d_in[9];
  const float* i_out_w = (const float*)d_in[10];
  const float* i_out_b = (const float*)d_in[11];
  float* out = (float*)d_out;

  const long DD = 1024L*1024L;
  char* ws = (char*)d_ws;
  short* s_bf    = (short*)ws; ws += 16384L*1024*2;
  short* W_all   = (short*)ws; ws += 3*DD*2;      // rows: [fuse_w; Wt2; Wi2]
  short* wvT     = (short*)ws; ws += 2*DD*2;      // [wvT_t; wvT_i]
  short* fuse_wT = (short*)ws; ws += DD*2;
  short* outw_st = (short*)ws; ws += 2*DD*2;      // [t_out_w; i_out_w] bf16
  short* Wc_st   = (short*)ws; ws += 2*DD*2;      // [Wc_t; Wc_i]
  float* bc      = (float*)ws; ws += 2048*4;
  float* b_all   = (float*)ws; ws += 3072*4;

  // prep
  k_addcvt<<<8192, 256, 0, stream>>>(text, image, s_bf);
  k_prep<<<6656, 256, 0, stream>>>(fuse_w, W_all,
                                   t_out_w, outw_st,
                                   i_out_w, outw_st + DD,
                                   t_in_w + 2*DD, wvT,
                                   i_in_w + 2*DD, wvT + DD,
                                   fuse_w, fuse_wT,
                                   t_out_w, t_in_b + 2048, t_out_b,
                                   i_out_w, i_in_b + 2048, i_out_b, bc);

  // Wc_z = out_w_z @ wv_z
  gemm_nt_small<<<dim3(8,8,2), 256, 0, stream>>>(outw_st, wvT, Wc_st,
                                                 1024, 1024, 1024, DD, DD, DD);
  // b_all[1024..3072) = Wc @ fuse_b + bc ; b_all[0..1024) = fuse_b
  k_bias2c<<<516, 256, 0, stream>>>(Wc_st, fuse_b, bc, b_all);
  // [Wt2; Wi2] = Wc @ fuse_w
  gemm_nt_small<<<dim3(16,8,1), 256, 0, stream>>>(Wc_st, fuse_wT, W_all + DD,
                                                  2048, 1024, 1024, 0, 0, 0);
  // main: C = s @ W_all.T + b_all, scatter into d_out
  gemm_main<<<dim3(768), 512, 0, stream>>>(s_bf, W_all, out, b_all, 16384, 3072, 1024);
}

// Round 10
// 215.595 us; speedup vs baseline: 1.0811x; 1.0560x over previous
//
#include <hip/hip_runtime.h>
#include <stdint.h>

typedef float f32x4 __attribute__((ext_vector_type(4)));
typedef short s16x8 __attribute__((ext_vector_type(8)));
typedef short s16x4 __attribute__((ext_vector_type(4)));

__device__ __forceinline__ short f2bf(float f){
  union { float f; unsigned u; } v; v.f = f;
  unsigned r = v.u + 0x7FFFu + ((v.u >> 16) & 1u);
  return (short)(r >> 16);
}
__device__ __forceinline__ float bf2f(short h){
  union { unsigned u; float f; } v; v.u = ((unsigned)(unsigned short)h) << 16;
  return v.f;
}

// ---------- fused prep: addcvt (blocks 0..8191), cvt x3 (8192..11263),
// transcvt x3 (11264..14335), bias1 (14336..14847) ----------
__global__ void k_prep(const float* __restrict__ ta, const float* __restrict__ tb,
                       short* __restrict__ so,
                       const float* __restrict__ c0s, short* __restrict__ c0d,
                       const float* __restrict__ c1s, short* __restrict__ c1d,
                       const float* __restrict__ c2s, short* __restrict__ c2d,
                       const float* __restrict__ t0s, short* __restrict__ t0d,
                       const float* __restrict__ t1s, short* __restrict__ t1d,
                       const float* __restrict__ t2s, short* __restrict__ t2d,
                       const float* __restrict__ wt, const float* __restrict__ bvt, const float* __restrict__ obt,
                       const float* __restrict__ wi, const float* __restrict__ bvi, const float* __restrict__ obi,
                       float* __restrict__ bc){
  int bid = blockIdx.x;
  int tid = threadIdx.x;
  if (bid < 8192) {
    long i = (long)bid * 256 + tid;
    const f32x4* a4 = (const f32x4*)ta;
    const f32x4* b4 = (const f32x4*)tb;
    f32x4 x0 = a4[2*i], x1 = a4[2*i+1];
    f32x4 y0 = b4[2*i], y1 = b4[2*i+1];
    s16x8 r;
    #pragma unroll
    for (int j=0;j<4;j++){ r[j] = f2bf(x0[j]+y0[j]); r[j+4] = f2bf(x1[j]+y1[j]); }
    *(s16x8*)(so + i*8) = r;
    return;
  }
  bid -= 8192;
  if (bid < 3072) {
    int z = bid >> 10, b = bid & 1023;
    const float* in = (z==0) ? c0s : ((z==1) ? c1s : c2s);
    short* out      = (z==0) ? c0d : ((z==1) ? c1d : c2d);
    long i = (long)b*256 + tid;
    f32x4 v = ((const f32x4*)in)[i];
    s16x4 r;
    #pragma unroll
    for (int j=0;j<4;j++) r[j] = f2bf(v[j]);
    *(s16x4*)(out + i*4) = r;
  } else if (bid < 6144) {
    int q = bid - 3072;
    int z = q >> 10, b = q & 1023;
    const float* in = (z==0) ? t0s : ((z==1) ? t1s : t2s);
    short* out      = (z==0) ? t0d : ((z==1) ? t1d : t2d);
    __shared__ float tile[32][33];
    int tx = tid & 31, ty = tid >> 5;
    int c0 = (b & 31)*32, r0 = (b >> 5)*32;
    #pragma unroll
    for (int i=ty; i<32; i+=8)
      tile[i][tx] = in[(long)(r0+i)*1024 + c0 + tx];
    __syncthreads();
    #pragma unroll
    for (int i=ty; i<32; i+=8)
      out[(long)(c0+i)*1024 + r0 + tx] = f2bf(tile[tx][i]);
  } else {
    int q = bid - 6144;
    int z = q >> 8, b = q & 255;
    const float* w  = z ? wi  : wt;
    const float* bv = z ? bvi : bvt;
    const float* ob = z ? obi : obt;
    int n = b*4 + (tid>>6);
    int lane = tid & 63;
    const float* row = w + (long)n*1024;
    float acc = 0.f;
    for (int j=lane; j<1024; j+=64) acc += row[j]*bv[j];
    #pragma unroll
    for (int m=32;m;m>>=1) acc += __shfl_xor(acc, m, 64);
    if (lane==0) bc[z*1024+n] = acc + ob[n];
  }
}

#define GLDS(src, dst) __builtin_amdgcn_global_load_lds( \
    (const __attribute__((address_space(1))) void*)(src), \
    (__attribute__((address_space(3))) void*)(dst), 16, 0, 0)

// ---------- small NT GEMM body (128x128 tile, m97 structure): C bf16 = A@B^T ----------
__device__ __forceinline__
void gemm_small_body(const short* __restrict__ A, const short* __restrict__ B,
                     short* __restrict__ C, int N, int K, int m0, int n0,
                     short* ldsA, short* ldsB, int tid)
{
  const int lane = tid & 63;
  const int wv = tid >> 6;
  const int wm = wv >> 1, wn = wv & 1;

  f32x4 acc[4][4];
  #pragma unroll
  for (int i=0;i<4;i++)
    #pragma unroll
    for (int j=0;j<4;j++) acc[i][j] = (f32x4){0.f,0.f,0.f,0.f};

  const int bo0 = wv*1024 + lane*16;
  const int bo1 = bo0 + 4096;
  const int r0 = bo0 >> 6, c0 = bo0 & 63;
  const int r1 = bo1 >> 6, c1 = bo1 & 63;
  const long rsb = (long)K * 2;

  const char* Ab = (const char*)A;
  const char* Bb = (const char*)B;
  char* lA = (char*)ldsA;
  char* lB = (char*)ldsB;

  const int nkt = K >> 5;
  for (int kt = 0; kt < nkt; ++kt) {
    const long kb = (long)kt * 64;
    GLDS(Ab + (long)(m0 + r0)*rsb + kb + c0, lA + wv*1024);
    GLDS(Ab + (long)(m0 + r1)*rsb + kb + c1, lA + 4096 + wv*1024);
    GLDS(Bb + (long)(n0 + r0)*rsb + kb + c0, lB + wv*1024);
    GLDS(Bb + (long)(n0 + r1)*rsb + kb + c1, lB + 4096 + wv*1024);
    __syncthreads();

    s16x8 af[4], bfv[4];
    #pragma unroll
    for (int i=0;i<4;i++)
      af[i] = *(const s16x8*)(lA + (wm*64 + i*16 + (lane&15))*64 + (lane>>4)*16);
    #pragma unroll
    for (int j=0;j<4;j++)
      bfv[j] = *(const s16x8*)(lB + (wn*64 + j*16 + (lane&15))*64 + (lane>>4)*16);

    #pragma unroll
    for (int i=0;i<4;i++)
      #pragma unroll
      for (int j=0;j<4;j++)
        acc[i][j] = __builtin_amdgcn_mfma_f32_16x16x32_bf16(af[i], bfv[j], acc[i][j], 0, 0, 0);
    __syncthreads();
  }

  #pragma unroll
  for (int j=0;j<4;j++){
    int gn = n0 + wn*64 + j*16 + (lane&15);
    #pragma unroll
    for (int i=0;i<4;i++){
      int gmb = m0 + wm*64 + i*16 + ((lane>>4)*4);
      #pragma unroll
      for (int r=0;r<4;r++)
        C[(long)(gmb+r)*N + gn] = f2bf(acc[i][j][r]);
    }
  }
}

// launch 1: Wc_z = out_w_z @ wv_z (z batches via blockIdx.z)
__global__ __launch_bounds__(256, 2)
void gemm_wc(const short* __restrict__ Abase, const short* __restrict__ Bbase,
             short* __restrict__ Cbase, long zA, long zB, long zC)
{
  __shared__ __align__(16) short ldsA[128*32];
  __shared__ __align__(16) short ldsB[128*32];
  gemm_small_body(Abase + (long)blockIdx.z*zA, Bbase + (long)blockIdx.z*zB,
                  Cbase + (long)blockIdx.z*zC, 1024, 1024,
                  blockIdx.x*128, blockIdx.y*128, ldsA, ldsB, threadIdx.x);
}

// launch 2 (merged): blocks 0..515 = bias2+copy; 516..643 = W2 = Wc @ fuse_w
__global__ __launch_bounds__(256, 2)
void k_b2g2(const short* __restrict__ Wc, const float* __restrict__ fuse_b,
            const float* __restrict__ bc, float* __restrict__ b_all,
            const short* __restrict__ fuse_wT, short* __restrict__ W2)
{
  __shared__ __align__(16) short ldsA[128*32];
  __shared__ __align__(16) short ldsB[128*32];
  int bid = blockIdx.x;
  if (bid < 512) {
    int n = bid*4 + (threadIdx.x>>6);
    int lane = threadIdx.x & 63;
    const short* row = Wc + (long)n*1024;
    float acc = 0.f;
    for (int j=lane; j<1024; j+=64) acc += bf2f(row[j])*fuse_b[j];
    #pragma unroll
    for (int m=32;m;m>>=1) acc += __shfl_xor(acc, m, 64);
    if (lane==0) b_all[1024+n] = acc + bc[n];
    return;
  }
  if (bid < 516) {
    int i = (bid - 512)*256 + threadIdx.x;
    b_all[i] = fuse_b[i];
    return;
  }
  int g = bid - 516;                 // 0..127 -> 16 x 8 tiles of 2048x1024
  gemm_small_body(Wc, fuse_wT, W2, 1024, 1024,
                  (g & 15)*128, (g >> 4)*128, ldsA, ldsB, threadIdx.x);
}

// ---------- main NT GEMM: 256x256, BK=64, 2 phases/K-tile (R7 verified) ----------
// LDS: Abuf0 @0, Abuf1 @32768, Bbuf0 @65536, Bbuf1 @98304 (32 KB each).
// Swizzle: 16B-chunk s of row r stored at s^(r&7); conflict-free (verified: 0).
//   ks0 phase of tile t: read B(t) x8 + A(t,ks0) x8; VMW4(no-op); bar;
//                        stage A(t+1)->Abuf[(t+1)&1]; lgkm0; 32 MFMA.
//   ks1 phase of tile t: read A(t,ks1) x8; VMW0 (drains B(t+1)+A(t+1)); bar;
//                        stage B(t+2)->Bbuf[t&1]; lgkm0; 32 MFMA.
// Read/write safety invariants verified R6/R7 (queue-trace in R6 notes).
#define MFMA16 __builtin_amdgcn_mfma_f32_16x16x32_bf16
#define VMW4 asm volatile("s_waitcnt vmcnt(4)" ::: "memory")
#define VMW0 asm volatile("s_waitcnt vmcnt(0)" ::: "memory")
#define LGKM0 asm volatile("s_waitcnt lgkmcnt(0)" ::: "memory")
#define MEMF asm volatile("" ::: "memory")

__global__ __launch_bounds__(512, 2)
void gemm_main(const short* __restrict__ A, const short* __restrict__ B,
               float* __restrict__ O, const float* __restrict__ bias,
               int M, int N, int K)
{
  __shared__ __align__(16) char lds[131072];

  const int nbn = N >> 8;
  const int nwg = (M >> 8) * nbn;
  const int cpx = nwg >> 3;
  int bid = blockIdx.x;
  int swz = (bid & 7) * cpx + (bid >> 3);
  const int m0 = (swz / nbn) << 8;
  const int n0 = (swz % nbn) << 8;

  const int tid  = threadIdx.x;
  const int lane = tid & 63;
  const int wid  = tid >> 6;
  const int wm   = wid >> 2;   // 0..1
  const int wn   = wid & 3;    // 0..3
  const long rsb = (long)K * 2;
  const char* Ab = (const char*)A;
  const char* Bb = (const char*)B;

  f32x4 acc[8][4];
  #pragma unroll
  for (int i=0;i<8;i++)
    #pragma unroll
    for (int j=0;j<4;j++) acc[i][j] = (f32x4){0.f,0.f,0.f,0.f};

  // Stage source precompute: linear LDS dest chunk c receives logical chunk
  // q = c ^ ((c>>3)&7)  (row preserved; inverse of the read swizzle).
  int srow[2][2]; int scol[2][2]; int sdst[2][2];
  #pragma unroll
  for (int H=0;H<2;H++)
    #pragma unroll
    for (int sb=0;sb<2;sb++){
      int c = H*1024 + sb*512 + wid*64 + lane;
      int q = c ^ ((c>>3)&7);
      srow[H][sb] = q >> 3;
      scol[H][sb] = (q & 7) << 4;
      sdst[H][sb] = (H*1024 + sb*512 + wid*64) << 4;
    }

  auto stage = [&](const char* P, int tr0, int s /*K-tile*/, int RB, int H){
    const long ktb = (long)s << 7;
    GLDS(P + ((long)(tr0 + srow[H][0]))*rsb + ktb + scol[H][0], lds + RB + sdst[H][0]);
    GLDS(P + ((long)(tr0 + srow[H][1]))*rsb + ktb + scol[H][1], lds + RB + sdst[H][1]);
  };

  const int swx = (lane & 7) << 4;   // read swizzle (row&7 == lane&7 for all frags)
  auto ldA = [&](int RB, int i, int ks) -> s16x8 {
    int off = (wm*128 + i*16 + (lane&15))*128 + ks*64 + ((lane>>4)<<4);
    off ^= swx;
    return *(const s16x8*)(lds + RB + off);
  };
  auto ldB = [&](int RB, int j, int ks) -> s16x8 {
    int off = (wn*64 + j*16 + (lane&15))*128 + ks*64 + ((lane>>4)<<4);
    off ^= swx;
    return *(const s16x8*)(lds + 65536 + RB + off);
  };

  s16x8 bfr[4][2];
  s16x8 af[8];
  const int nkt = K >> 6;  // 16 for K=1024

  // Prologue: A(0)->Abuf0, B(0)->Bbuf0, B(1)->Bbuf1; VMW4 drains A(0)+B(0),
  // leaves B(1)x4 in flight (drained at ph(0,ks1) VMW0).
  stage(Ab, m0, 0, 0,     0); stage(Ab, m0, 0, 0,     1);
  stage(Bb, n0, 0, 65536, 0); stage(Bb, n0, 0, 65536, 1);
  stage(Bb, n0, 1, 98304, 0); stage(Bb, n0, 1, 98304, 1);
  VMW4; MEMF;
  __builtin_amdgcn_s_barrier();

  for (int t = 0; t < nkt; ++t) {
    const int RB = (t & 1) << 15;
    // -------- ks0 phase --------
    #pragma unroll
    for (int j=0;j<4;j++){ bfr[j][0] = ldB(RB, j, 0); bfr[j][1] = ldB(RB, j, 1); }
    #pragma unroll
    for (int i=0;i<8;i++) af[i] = ldA(RB, i, 0);
    VMW4; MEMF;
    __builtin_amdgcn_s_barrier();
    if (t+1 < nkt) {
      const int AB2 = ((t+1)&1) << 15;
      stage(Ab, m0, t+1, AB2, 0); stage(Ab, m0, t+1, AB2, 1);
    }
    LGKM0;
    __builtin_amdgcn_s_setprio(1);
    #pragma unroll
    for (int i=0;i<8;i++)
      #pragma unroll
      for (int j=0;j<4;j++)
        acc[i][j] = MFMA16(af[i], bfr[j][0], acc[i][j], 0, 0, 0);
    __builtin_amdgcn_s_setprio(0);
    // -------- ks1 phase --------
    #pragma unroll
    for (int i=0;i<8;i++) af[i] = ldA(RB, i, 1);
    VMW0; MEMF;            // drains B(t+1) AND A(t+1) before the barrier
    __builtin_amdgcn_s_barrier();
    if (t+2 < nkt) {
      const int BB2 = 65536 + RB;   // Bbuf[t&1]: all its reads done at ks0
      stage(Bb, n0, t+2, BB2, 0); stage(Bb, n0, t+2, BB2, 1);
    }
    LGKM0;
    __builtin_amdgcn_s_setprio(1);
    #pragma unroll
    for (int i=0;i<8;i++)
      #pragma unroll
      for (int j=0;j<4;j++)
        acc[i][j] = MFMA16(af[i], bfr[j][1], acc[i][j], 0, 0, 0);
    __builtin_amdgcn_s_setprio(0);
  }

  // Epilogue: fp32 + bias, scatter by output region (text | image | fused).
  const long BD = (long)M * 1024L;
  #pragma unroll
  for (int j=0;j<4;j++){
    int gn = n0 + wn*64 + j*16 + (lane&15);
    float bb = bias[gn];
    int region = gn >> 10;
    long rbase = (region==0) ? 2*BD : ((region==1) ? 0L : BD);
    int col = gn & 1023;
    #pragma unroll
    for (int i=0;i<8;i++){
      int gr = m0 + wm*128 + i*16 + ((lane>>4)<<2);
      #pragma unroll
      for (int r=0;r<4;r++)
        O[rbase + (long)(gr+r)*1024 + col] = acc[i][j][r] + bb;
    }
  }
}

extern "C" void kernel_launch(void* const* d_in, const int* in_sizes, int n_in,
                              void* d_out, int out_size, void* d_ws, size_t ws_size,
                              hipStream_t stream) {
  const float* text    = (const float*)d_in[0];
  const float* image   = (const float*)d_in[1];
  const float* fuse_w  = (const float*)d_in[2];
  const float* fuse_b  = (const float*)d_in[3];
  const float* t_in_w  = (const float*)d_in[4];
  const float* t_in_b  = (const float*)d_in[5];
  const float* t_out_w = (const float*)d_in[6];
  const float* t_out_b = (const float*)d_in[7];
  const float* i_in_w  = (const float*)d_in[8];
  const float* i_in_b  = (const float*)d_in[9];
  const float* i_out_w = (const float*)d_in[10];
  const float* i_out_b = (const float*)d_in[11];
  float* out = (float*)d_out;

  const long DD = 1024L*1024L;
  char* ws = (char*)d_ws;
  short* s_bf    = (short*)ws; ws += 16384L*1024*2;
  short* W_all   = (short*)ws; ws += 3*DD*2;      // rows: [fuse_w; Wt2; Wi2]
  short* wvT     = (short*)ws; ws += 2*DD*2;      // [wvT_t; wvT_i]
  short* fuse_wT = (short*)ws; ws += DD*2;
  short* outw_st = (short*)ws; ws += 2*DD*2;      // [t_out_w; i_out_w] bf16
  short* Wc_st   = (short*)ws; ws += 2*DD*2;      // [Wc_t; Wc_i]
  float* bc      = (float*)ws; ws += 2048*4;
  float* b_all   = (float*)ws; ws += 3072*4;

  // launch 1: all elementwise prep (addcvt + cvt + transcvt + bias1)
  k_prep<<<14848, 256, 0, stream>>>(text, image, s_bf,
                                    fuse_w, W_all,
                                    t_out_w, outw_st,
                                    i_out_w, outw_st + DD,
                                    t_in_w + 2*DD, wvT,
                                    i_in_w + 2*DD, wvT + DD,
                                    fuse_w, fuse_wT,
                                    t_out_w, t_in_b + 2048, t_out_b,
                                    i_out_w, i_in_b + 2048, i_out_b, bc);

  // launch 2: Wc_z = out_w_z @ wv_z
  gemm_wc<<<dim3(8,8,2), 256, 0, stream>>>(outw_st, wvT, Wc_st, DD, DD, DD);

  // launch 3 (merged): b_all = [fuse_b ; Wc@fuse_b + bc] AND W2 = Wc @ fuse_w
  k_b2g2<<<644, 256, 0, stream>>>(Wc_st, fuse_b, bc, b_all, fuse_wT, W_all + DD);

  // launch 4: main C = s @ W_all.T + b_all, scatter into d_out
  gemm_main<<<dim3(768), 512, 0, stream>>>(s_bf, W_all, out, b_all, 16384, 3072, 1024);
}